// Round 8
// baseline (122.809 us; speedup 1.0000x reference)
//
#include <hip/hip_runtime.h>

// B=4, CIN=COUT=64, H=W=128, 3x3 deformable conv, fp32 in/out.
// R7 base + R8 delta: stage-2 main loop made branch-free. All 9 k2 coord
// sets (bilinear weights + clamped tile base + oob bit) precomputed into
// registers; the hot loop is pure ds_read/blend/pack/MFMA so the scheduler
// can software-pipeline it; the exact out-of-tile correction (|offset|>=2,
// ~8 sigma, never taken on real data) moved to a cold post-loop pass under
// one wave-uniform __any.

typedef __attribute__((ext_vector_type(8))) short short8x;
typedef __attribute__((ext_vector_type(4))) float float4x;
typedef unsigned short ushort;
typedef unsigned int uint;

__device__ __forceinline__ ushort f2bf(float f) {
    uint b = __float_as_uint(f);
    b += 0x7fffu + ((b >> 16) & 1u);
    return (ushort)(b >> 16);
}
__device__ __forceinline__ float bf2f(ushort u) {
    return __uint_as_float(((uint)u) << 16);
}

// ---------------------------------------------------------------------------
// Prologue: pack weights into MFMA B-fragment order (bf16). (R5 verbatim)
//  Bd [kk(18)][nt(4)][lane(64)][i(8)]: n = nt*16+(lane&15),
//     k = kk*32 + (lane>>4)*8 + i -> k2 = kk>>1, cin = (kk&1)*32+(lane>>4)*8+i
//  Bo [kk(18)][nt(2)][lane][i]: same, n>=18 zero-padded.
// ---------------------------------------------------------------------------
__global__ __launch_bounds__(256) void pack_weights(
    const float* __restrict__ w_def, const float* __restrict__ w_off,
    ushort* __restrict__ Bd, ushort* __restrict__ Bo) {
    int idx = blockIdx.x * 256 + threadIdx.x;
    if (idx < 36864) {
        int i = idx & 7;
        int lane = (idx >> 3) & 63;
        int nt = (idx >> 9) & 3;
        int kk = idx >> 11;
        int n = (nt << 4) + (lane & 15);
        int k2 = kk >> 1;
        int cin = ((kk & 1) << 5) + ((lane >> 4) << 3) + i;
        Bd[idx] = f2bf(w_def[(n * 64 + cin) * 9 + k2]);
    } else if (idx < 36864 + 18432) {
        int d = idx - 36864;
        int i = d & 7;
        int lane = (d >> 3) & 63;
        int nt = (d >> 9) & 1;
        int kk = d >> 10;
        int n = (nt << 4) + (lane & 15);
        int k2 = kk >> 1;
        int cin = ((kk & 1) << 5) + ((lane >> 4) << 3) + i;
        Bo[d] = (n < 18) ? f2bf(w_off[(n * 64 + cin) * 9 + k2]) : (ushort)0;
    }
}

// ---------------------------------------------------------------------------
// Fused kernel. Block = 8x8 pixel tile, 256 threads = 4 waves (M-split:
// wave w owns pixels 16w..16w+15).
// ---------------------------------------------------------------------------
__global__ __launch_bounds__(256, 4) void dcn_fused(
    const float* __restrict__ x, const ushort* __restrict__ Bd,
    const ushort* __restrict__ Bo, const float* __restrict__ boff,
    const float* __restrict__ bdef, float* __restrict__ out) {

    int tid = threadIdx.x;
    int lane = tid & 63, wv = tid >> 6;
    int blk = blockIdx.x;
    int b = blk >> 8, t = blk & 255;
    int h0 = (t >> 4) << 3, w0 = (t & 15) << 3;

    // tile[pos(225, stride 72)][cin(64)+pad8] bf16: 32400 B.
    __shared__ __align__(16) ushort tile[225 * 72];
    __shared__ float offl[64 * 18];  // [px][ch] offsets, 4608 B

    const float* xb = x + ((long)b << 20);

    // ---- stage halo (R5 verbatim): thread = one pos, reads 64 planes.
    if (tid < 225) {
        int ty = tid / 15, tx = tid - ty * 15;
        int y = h0 - 3 + ty, xx = w0 - 3 + tx;
        bool valid = ((unsigned)y < 128u) & ((unsigned)xx < 128u);
        int yc = min(max(y, 0), 127), xc = min(max(xx, 0), 127);
        const float* gp = xb + (yc << 7) + xc;
        uint* trow = (uint*)&tile[tid * 72];
#pragma unroll
        for (int c8 = 0; c8 < 8; ++c8) {
            uint4 d;
            float v0 = valid ? gp[(c8 * 8 + 0) << 14] : 0.f;
            float v1 = valid ? gp[(c8 * 8 + 1) << 14] : 0.f;
            float v2 = valid ? gp[(c8 * 8 + 2) << 14] : 0.f;
            float v3 = valid ? gp[(c8 * 8 + 3) << 14] : 0.f;
            float v4 = valid ? gp[(c8 * 8 + 4) << 14] : 0.f;
            float v5 = valid ? gp[(c8 * 8 + 5) << 14] : 0.f;
            float v6 = valid ? gp[(c8 * 8 + 6) << 14] : 0.f;
            float v7 = valid ? gp[(c8 * 8 + 7) << 14] : 0.f;
            d.x = (uint)f2bf(v0) | ((uint)f2bf(v1) << 16);
            d.y = (uint)f2bf(v2) | ((uint)f2bf(v3) << 16);
            d.z = (uint)f2bf(v4) | ((uint)f2bf(v5) << 16);
            d.w = (uint)f2bf(v6) | ((uint)f2bf(v7) << 16);
            *(uint4*)&trow[c8 * 4] = d;
        }
    }
    __syncthreads();

    int l15 = lane & 15, lq = lane >> 4;
    int p1 = (wv << 4) + l15;          // this lane's A-row pixel
    int plh = p1 >> 3, plw = p1 & 7;

    // ---- stage 1: offset conv via MFMA (R5 verbatim)
    float4x oacc0 = {0.f, 0.f, 0.f, 0.f}, oacc1 = {0.f, 0.f, 0.f, 0.f};
#pragma unroll
    for (int k2 = 0; k2 < 9; ++k2) {
        int kh = k2 / 3, kw = k2 - kh * 3;
        int pos = (plh + 2 + kh) * 15 + (plw + 2 + kw);
        int abase = pos * 72 + (lq << 3);
#pragma unroll
        for (int half = 0; half < 2; ++half) {
            int kk = k2 * 2 + half;
            short8x a = *(const short8x*)&tile[abase + half * 32];
            short8x b0 = *(const short8x*)&Bo[(kk * 2 + 0) * 512 + (lane << 3)];
            short8x b1 = *(const short8x*)&Bo[(kk * 2 + 1) * 512 + (lane << 3)];
            oacc0 = __builtin_amdgcn_mfma_f32_16x16x32_bf16(a, b0, oacc0, 0, 0, 0);
            oacc1 = __builtin_amdgcn_mfma_f32_16x16x32_bf16(a, b1, oacc1, 0, 0, 0);
        }
    }
    {   // scatter D (col n = lane&15 [+16], row = lq*4+r) + bias -> offl[px][ch]
        int n0 = l15, n1 = 16 + l15;
        float bo0 = boff[n0];
        float bo1 = (n1 < 18) ? boff[n1] : 0.f;
#pragma unroll
        for (int r = 0; r < 4; ++r) {
            int p = (wv << 4) + (lq << 2) + r;
            offl[p * 18 + n0] = oacc0[r] + bo0;
            if (n1 < 18) offl[p * 18 + n1] = oacc1[r] + bo1;
        }
    }
    __syncthreads();

    // ---- prefetch this pixel's 9 offset pairs to registers
    float2 offr[9];
#pragma unroll
    for (int k2 = 0; k2 < 9; ++k2)
        offr[k2] = *(const float2*)&offl[p1 * 18 + k2 * 2];

    // ---- R8: precompute all 9 coord sets (weights, clamped base, oob bit)
    float4x wk[9];
    int basek[9];
    uint oobmask = 0;
#pragma unroll
    for (int k2 = 0; k2 < 9; ++k2) {
        const int kh = k2 / 3, kw = k2 - kh * 3;
        float sy = (float)(plh + 2 + kh) + offr[k2].x;
        float sx = (float)(plw + 2 + kw) + offr[k2].y;
        float yf = floorf(sy), xf = floorf(sx);
        int by = (int)yf, bx = (int)xf;
        float wy1 = sy - yf, wx1 = sx - xf;
        float wy0 = 1.f - wy1, wx0 = 1.f - wx1;
        wk[k2] = (float4x){wy0 * wx0, wy0 * wx1, wy1 * wx0, wy1 * wx1};
        bool oob = ((unsigned)by > 13u) | ((unsigned)bx > 13u);
        oobmask |= oob ? (1u << k2) : 0u;
        int byc = min(max(by, 0), 13), bxc = min(max(bx, 0), 13);
        basek[k2] = (byc * 15 + bxc) * 72 + (lq << 3);
    }

    // ---- stage 2 main loop: branch-free gather/blend/pack/MFMA
    float4x acc[4];
#pragma unroll
    for (int nt = 0; nt < 4; ++nt) acc[nt] = (float4x){0.f, 0.f, 0.f, 0.f};

#pragma unroll
    for (int k2 = 0; k2 < 9; ++k2) {
        float w00 = wk[k2][0], w01 = wk[k2][1];
        float w10 = wk[k2][2], w11 = wk[k2][3];
        int base = basek[k2];
#pragma unroll
        for (int half = 0; half < 2; ++half) {
            int kk = k2 * 2 + half;
            int cb = base + half * 32;
            short8x c00 = *(const short8x*)&tile[cb];
            short8x c01 = *(const short8x*)&tile[cb + 72];
            short8x c10 = *(const short8x*)&tile[cb + 72 * 15];
            short8x c11 = *(const short8x*)&tile[cb + 72 * 16];
            float s[8];
#pragma unroll
            for (int j = 0; j < 8; ++j) {
                s[j] = w00 * bf2f((ushort)c00[j]) + w01 * bf2f((ushort)c01[j])
                     + w10 * bf2f((ushort)c10[j]) + w11 * bf2f((ushort)c11[j]);
            }
            union { short8x v; ushort u[8]; } A;
#pragma unroll
            for (int j = 0; j < 8; ++j) A.u[j] = f2bf(s[j]);
#pragma unroll
            for (int nt = 0; nt < 4; ++nt) {
                short8x bw = *(const short8x*)&Bd[(kk * 4 + nt) * 512 + (lane << 3)];
                acc[nt] = __builtin_amdgcn_mfma_f32_16x16x32_bf16(A.v, bw, acc[nt], 0, 0, 0);
            }
        }
    }

    // ---- cold exactness pass: out-of-tile samples (|offset|>=2, ~8 sigma;
    // never taken on this data but kept for correctness). Subtract the
    // clamped-tile contribution, add the true global-memory sample.
    if (__any(oobmask != 0)) {
#pragma unroll 1
        for (int k2 = 0; k2 < 9; ++k2) {
            if (!__any((oobmask >> k2) & 1)) continue;
            bool oob = (oobmask >> k2) & 1;
            const int kh = k2 / 3, kw = k2 - kh * 3;
            float sy = (float)(plh + 2 + kh) + offr[k2].x;
            float sx = (float)(plw + 2 + kw) + offr[k2].y;
            int by = (int)floorf(sy), bx = (int)floorf(sx);
            float w00 = wk[k2][0], w01 = wk[k2][1];
            float w10 = wk[k2][2], w11 = wk[k2][3];
            int y0g = by + h0 - 3, x0g = bx + w0 - 3;
            int y1g = y0g + 1, x1g = x0g + 1;
            float m00 = ((unsigned)y0g < 128u && (unsigned)x0g < 128u) ? w00 : 0.f;
            float m01 = ((unsigned)y0g < 128u && (unsigned)x1g < 128u) ? w01 : 0.f;
            float m10 = ((unsigned)y1g < 128u && (unsigned)x0g < 128u) ? w10 : 0.f;
            float m11 = ((unsigned)y1g < 128u && (unsigned)x1g < 128u) ? w11 : 0.f;
            int y0c = min(max(y0g, 0), 127), y1c = min(max(y1g, 0), 127);
            int x0c = min(max(x0g, 0), 127), x1c = min(max(x1g, 0), 127);
            int i00 = (y0c << 7) + x0c, i01 = (y0c << 7) + x1c;
            int i10 = (y1c << 7) + x0c, i11 = (y1c << 7) + x1c;
            int base = basek[k2];
#pragma unroll
            for (int half = 0; half < 2; ++half) {
                int kk = k2 * 2 + half;
                int cb = base + half * 32;
                short8x c00 = *(const short8x*)&tile[cb];
                short8x c01 = *(const short8x*)&tile[cb + 72];
                short8x c10 = *(const short8x*)&tile[cb + 72 * 15];
                short8x c11 = *(const short8x*)&tile[cb + 72 * 16];
                int cin0 = half * 32 + (lq << 3);
                float d[8];
#pragma unroll
                for (int j = 0; j < 8; ++j) {
                    float sl = w00 * bf2f((ushort)c00[j]) + w01 * bf2f((ushort)c01[j])
                             + w10 * bf2f((ushort)c10[j]) + w11 * bf2f((ushort)c11[j]);
                    const float* xp = xb + ((long)(cin0 + j) << 14);
                    float sg = m00 * xp[i00] + m01 * xp[i01]
                             + m10 * xp[i10] + m11 * xp[i11];
                    d[j] = oob ? (sg - sl) : 0.f;
                }
                union { short8x v; ushort u[8]; } A;
#pragma unroll
                for (int j = 0; j < 8; ++j) A.u[j] = f2bf(d[j]);
#pragma unroll
                for (int nt = 0; nt < 4; ++nt) {
                    short8x bw = *(const short8x*)&Bd[(kk * 4 + nt) * 512 + (lane << 3)];
                    acc[nt] = __builtin_amdgcn_mfma_f32_16x16x32_bf16(A.v, bw, acc[nt], 0, 0, 0);
                }
            }
        }
    }

    // ---- epilogue (R5 verbatim): transpose D through LDS, coalesced stores
    __syncthreads();
    float* ob = (float*)tile;  // [64 px][65] f32 = 16640 B, aliases tile
#pragma unroll
    for (int nt = 0; nt < 4; ++nt) {
        int n = (nt << 4) + l15;
#pragma unroll
        for (int r = 0; r < 4; ++r) {
            int p = (wv << 4) + (lq << 2) + r;
            ob[p * 65 + n] = acc[nt][r];
        }
    }
    __syncthreads();
    {
        int n = tid >> 2, q = tid & 3;
        float bd = bdef[n];
        float* dst = out + (((long)(b * 64 + n)) << 14) + (h0 << 7) + w0;
#pragma unroll
        for (int rr = 0; rr < 2; ++rr) {
            int r = (q << 1) + rr;
            float v[8];
#pragma unroll
            for (int c = 0; c < 8; ++c) v[c] = ob[(r * 8 + c) * 65 + n] + bd;
            float4x s0 = {v[0], v[1], v[2], v[3]};
            float4x s1 = {v[4], v[5], v[6], v[7]};
            *(float4x*)(dst + (r << 7)) = s0;
            *(float4x*)(dst + (r << 7) + 4) = s1;
        }
    }
}

// ---------------------------------------------------------------------------
extern "C" void kernel_launch(void* const* d_in, const int* in_sizes, int n_in,
                              void* d_out, int out_size, void* d_ws, size_t ws_size,
                              hipStream_t stream) {
    const float* x     = (const float*)d_in[0];  // (4,64,128,128)
    const float* w_off = (const float*)d_in[1];  // (18,64,3,3)
    const float* b_off = (const float*)d_in[2];  // (18,)
    const float* w_def = (const float*)d_in[3];  // (64,64,3,3)
    const float* b_def = (const float*)d_in[4];  // (64,)
    float* out = (float*)d_out;                  // (4,64,128,128)

    ushort* Bd = (ushort*)d_ws;                  // 36864 bf16 = 73728 B
    ushort* Bo = Bd + 36864;                     // 18432 bf16 = 36864 B

    hipLaunchKernelGGL(pack_weights, dim3(216), dim3(256), 0, stream,
                       w_def, w_off, Bd, Bo);
    hipLaunchKernelGGL(dcn_fused, dim3(1024), dim3(256), 0, stream,
                       x, Bd, Bo, b_off, b_def, out);
}

// Round 9
// 112.670 us; speedup vs baseline: 1.0900x; 1.0900x over previous
//
#include <hip/hip_runtime.h>

// B=4, CIN=COUT=64, H=W=128, 3x3 deformable conv, fp32 in/out.
// R8 + single R9 delta: the cold out-of-tile pass recomputes its coords from
// LDS (offl) instead of dynamically indexing the precomputed register arrays
// wk[]/basek[]/offr[]. R8's dynamic indexing demoted those arrays to scratch
// (WRITE_SIZE 16->87 MB, main loop read bilinear weights from global scratch).
// Now they are constant-indexed only -> VGPR-resident -> the branch-free main
// loop can actually software-pipeline.

typedef __attribute__((ext_vector_type(8))) short short8x;
typedef __attribute__((ext_vector_type(4))) float float4x;
typedef unsigned short ushort;
typedef unsigned int uint;

__device__ __forceinline__ ushort f2bf(float f) {
    uint b = __float_as_uint(f);
    b += 0x7fffu + ((b >> 16) & 1u);
    return (ushort)(b >> 16);
}
__device__ __forceinline__ float bf2f(ushort u) {
    return __uint_as_float(((uint)u) << 16);
}

// ---------------------------------------------------------------------------
// Prologue: pack weights into MFMA B-fragment order (bf16). (R5 verbatim)
//  Bd [kk(18)][nt(4)][lane(64)][i(8)]: n = nt*16+(lane&15),
//     k = kk*32 + (lane>>4)*8 + i -> k2 = kk>>1, cin = (kk&1)*32+(lane>>4)*8+i
//  Bo [kk(18)][nt(2)][lane][i]: same, n>=18 zero-padded.
// ---------------------------------------------------------------------------
__global__ __launch_bounds__(256) void pack_weights(
    const float* __restrict__ w_def, const float* __restrict__ w_off,
    ushort* __restrict__ Bd, ushort* __restrict__ Bo) {
    int idx = blockIdx.x * 256 + threadIdx.x;
    if (idx < 36864) {
        int i = idx & 7;
        int lane = (idx >> 3) & 63;
        int nt = (idx >> 9) & 3;
        int kk = idx >> 11;
        int n = (nt << 4) + (lane & 15);
        int k2 = kk >> 1;
        int cin = ((kk & 1) << 5) + ((lane >> 4) << 3) + i;
        Bd[idx] = f2bf(w_def[(n * 64 + cin) * 9 + k2]);
    } else if (idx < 36864 + 18432) {
        int d = idx - 36864;
        int i = d & 7;
        int lane = (d >> 3) & 63;
        int nt = (d >> 9) & 1;
        int kk = d >> 10;
        int n = (nt << 4) + (lane & 15);
        int k2 = kk >> 1;
        int cin = ((kk & 1) << 5) + ((lane >> 4) << 3) + i;
        Bo[d] = (n < 18) ? f2bf(w_off[(n * 64 + cin) * 9 + k2]) : (ushort)0;
    }
}

// ---------------------------------------------------------------------------
// Fused kernel. Block = 8x8 pixel tile, 256 threads = 4 waves (M-split:
// wave w owns pixels 16w..16w+15).
// ---------------------------------------------------------------------------
__global__ __launch_bounds__(256, 4) void dcn_fused(
    const float* __restrict__ x, const ushort* __restrict__ Bd,
    const ushort* __restrict__ Bo, const float* __restrict__ boff,
    const float* __restrict__ bdef, float* __restrict__ out) {

    int tid = threadIdx.x;
    int lane = tid & 63, wv = tid >> 6;
    int blk = blockIdx.x;
    int b = blk >> 8, t = blk & 255;
    int h0 = (t >> 4) << 3, w0 = (t & 15) << 3;

    // tile[pos(225, stride 72)][cin(64)+pad8] bf16: 32400 B.
    __shared__ __align__(16) ushort tile[225 * 72];
    __shared__ float offl[64 * 18];  // [px][ch] offsets, 4608 B

    const float* xb = x + ((long)b << 20);

    // ---- stage halo (R5 verbatim): thread = one pos, reads 64 planes.
    if (tid < 225) {
        int ty = tid / 15, tx = tid - ty * 15;
        int y = h0 - 3 + ty, xx = w0 - 3 + tx;
        bool valid = ((unsigned)y < 128u) & ((unsigned)xx < 128u);
        int yc = min(max(y, 0), 127), xc = min(max(xx, 0), 127);
        const float* gp = xb + (yc << 7) + xc;
        uint* trow = (uint*)&tile[tid * 72];
#pragma unroll
        for (int c8 = 0; c8 < 8; ++c8) {
            uint4 d;
            float v0 = valid ? gp[(c8 * 8 + 0) << 14] : 0.f;
            float v1 = valid ? gp[(c8 * 8 + 1) << 14] : 0.f;
            float v2 = valid ? gp[(c8 * 8 + 2) << 14] : 0.f;
            float v3 = valid ? gp[(c8 * 8 + 3) << 14] : 0.f;
            float v4 = valid ? gp[(c8 * 8 + 4) << 14] : 0.f;
            float v5 = valid ? gp[(c8 * 8 + 5) << 14] : 0.f;
            float v6 = valid ? gp[(c8 * 8 + 6) << 14] : 0.f;
            float v7 = valid ? gp[(c8 * 8 + 7) << 14] : 0.f;
            d.x = (uint)f2bf(v0) | ((uint)f2bf(v1) << 16);
            d.y = (uint)f2bf(v2) | ((uint)f2bf(v3) << 16);
            d.z = (uint)f2bf(v4) | ((uint)f2bf(v5) << 16);
            d.w = (uint)f2bf(v6) | ((uint)f2bf(v7) << 16);
            *(uint4*)&trow[c8 * 4] = d;
        }
    }
    __syncthreads();

    int l15 = lane & 15, lq = lane >> 4;
    int p1 = (wv << 4) + l15;          // this lane's A-row pixel
    int plh = p1 >> 3, plw = p1 & 7;

    // ---- stage 1: offset conv via MFMA (R5 verbatim)
    float4x oacc0 = {0.f, 0.f, 0.f, 0.f}, oacc1 = {0.f, 0.f, 0.f, 0.f};
#pragma unroll
    for (int k2 = 0; k2 < 9; ++k2) {
        int kh = k2 / 3, kw = k2 - kh * 3;
        int pos = (plh + 2 + kh) * 15 + (plw + 2 + kw);
        int abase = pos * 72 + (lq << 3);
#pragma unroll
        for (int half = 0; half < 2; ++half) {
            int kk = k2 * 2 + half;
            short8x a = *(const short8x*)&tile[abase + half * 32];
            short8x b0 = *(const short8x*)&Bo[(kk * 2 + 0) * 512 + (lane << 3)];
            short8x b1 = *(const short8x*)&Bo[(kk * 2 + 1) * 512 + (lane << 3)];
            oacc0 = __builtin_amdgcn_mfma_f32_16x16x32_bf16(a, b0, oacc0, 0, 0, 0);
            oacc1 = __builtin_amdgcn_mfma_f32_16x16x32_bf16(a, b1, oacc1, 0, 0, 0);
        }
    }
    {   // scatter D (col n = lane&15 [+16], row = lq*4+r) + bias -> offl[px][ch]
        int n0 = l15, n1 = 16 + l15;
        float bo0 = boff[n0];
        float bo1 = (n1 < 18) ? boff[n1] : 0.f;
#pragma unroll
        for (int r = 0; r < 4; ++r) {
            int p = (wv << 4) + (lq << 2) + r;
            offl[p * 18 + n0] = oacc0[r] + bo0;
            if (n1 < 18) offl[p * 18 + n1] = oacc1[r] + bo1;
        }
    }
    __syncthreads();

    // ---- precompute all 9 coord sets into registers (constant-indexed ONLY;
    // the cold pass below recomputes from LDS so these never go to scratch)
    float4x wk[9];
    int basek[9];
    uint oobmask = 0;
#pragma unroll
    for (int k2 = 0; k2 < 9; ++k2) {
        const int kh = k2 / 3, kw = k2 - kh * 3;
        float2 od = *(const float2*)&offl[p1 * 18 + k2 * 2];
        float sy = (float)(plh + 2 + kh) + od.x;
        float sx = (float)(plw + 2 + kw) + od.y;
        float yf = floorf(sy), xf = floorf(sx);
        int by = (int)yf, bx = (int)xf;
        float wy1 = sy - yf, wx1 = sx - xf;
        float wy0 = 1.f - wy1, wx0 = 1.f - wx1;
        wk[k2] = (float4x){wy0 * wx0, wy0 * wx1, wy1 * wx0, wy1 * wx1};
        bool oob = ((unsigned)by > 13u) | ((unsigned)bx > 13u);
        oobmask |= oob ? (1u << k2) : 0u;
        int byc = min(max(by, 0), 13), bxc = min(max(bx, 0), 13);
        basek[k2] = (byc * 15 + bxc) * 72 + (lq << 3);
    }

    // ---- stage 2 main loop: branch-free gather/blend/pack/MFMA
    float4x acc[4];
#pragma unroll
    for (int nt = 0; nt < 4; ++nt) acc[nt] = (float4x){0.f, 0.f, 0.f, 0.f};

#pragma unroll
    for (int k2 = 0; k2 < 9; ++k2) {
        float w00 = wk[k2][0], w01 = wk[k2][1];
        float w10 = wk[k2][2], w11 = wk[k2][3];
        int base = basek[k2];
#pragma unroll
        for (int half = 0; half < 2; ++half) {
            int kk = k2 * 2 + half;
            int cb = base + half * 32;
            short8x c00 = *(const short8x*)&tile[cb];
            short8x c01 = *(const short8x*)&tile[cb + 72];
            short8x c10 = *(const short8x*)&tile[cb + 72 * 15];
            short8x c11 = *(const short8x*)&tile[cb + 72 * 16];
            float s[8];
#pragma unroll
            for (int j = 0; j < 8; ++j) {
                s[j] = w00 * bf2f((ushort)c00[j]) + w01 * bf2f((ushort)c01[j])
                     + w10 * bf2f((ushort)c10[j]) + w11 * bf2f((ushort)c11[j]);
            }
            union { short8x v; ushort u[8]; } A;
#pragma unroll
            for (int j = 0; j < 8; ++j) A.u[j] = f2bf(s[j]);
#pragma unroll
            for (int nt = 0; nt < 4; ++nt) {
                short8x bw = *(const short8x*)&Bd[(kk * 4 + nt) * 512 + (lane << 3)];
                acc[nt] = __builtin_amdgcn_mfma_f32_16x16x32_bf16(A.v, bw, acc[nt], 0, 0, 0);
            }
        }
    }

    // ---- cold exactness pass: out-of-tile samples (|offset|>=2, ~8 sigma;
    // never taken on this data). Recomputes EVERYTHING from offl (LDS) —
    // no dynamic indexing of the register arrays above.
    if (__any(oobmask != 0)) {
#pragma unroll 1
        for (int k2 = 0; k2 < 9; ++k2) {
            if (!__any((oobmask >> k2) & 1)) continue;
            bool oob = (oobmask >> k2) & 1;
            const int kh = k2 / 3, kw = k2 - kh * 3;
            float2 od = *(const float2*)&offl[p1 * 18 + k2 * 2];
            float sy = (float)(plh + 2 + kh) + od.x;
            float sx = (float)(plw + 2 + kw) + od.y;
            float yf = floorf(sy), xf = floorf(sx);
            int by = (int)yf, bx = (int)xf;
            float wy1 = sy - yf, wx1 = sx - xf;
            float wy0 = 1.f - wy1, wx0 = 1.f - wx1;
            float w00 = wy0 * wx0, w01 = wy0 * wx1;
            float w10 = wy1 * wx0, w11 = wy1 * wx1;
            int byc = min(max(by, 0), 13), bxc = min(max(bx, 0), 13);
            int base = (byc * 15 + bxc) * 72 + (lq << 3);
            int y0g = by + h0 - 3, x0g = bx + w0 - 3;
            int y1g = y0g + 1, x1g = x0g + 1;
            float m00 = ((unsigned)y0g < 128u && (unsigned)x0g < 128u) ? w00 : 0.f;
            float m01 = ((unsigned)y0g < 128u && (unsigned)x1g < 128u) ? w01 : 0.f;
            float m10 = ((unsigned)y1g < 128u && (unsigned)x0g < 128u) ? w10 : 0.f;
            float m11 = ((unsigned)y1g < 128u && (unsigned)x1g < 128u) ? w11 : 0.f;
            int y0c = min(max(y0g, 0), 127), y1c = min(max(y1g, 0), 127);
            int x0c = min(max(x0g, 0), 127), x1c = min(max(x1g, 0), 127);
            int i00 = (y0c << 7) + x0c, i01 = (y0c << 7) + x1c;
            int i10 = (y1c << 7) + x0c, i11 = (y1c << 7) + x1c;
#pragma unroll
            for (int half = 0; half < 2; ++half) {
                int kk = k2 * 2 + half;
                int cb = base + half * 32;
                short8x c00 = *(const short8x*)&tile[cb];
                short8x c01 = *(const short8x*)&tile[cb + 72];
                short8x c10 = *(const short8x*)&tile[cb + 72 * 15];
                short8x c11 = *(const short8x*)&tile[cb + 72 * 16];
                int cin0 = half * 32 + (lq << 3);
                float d[8];
#pragma unroll
                for (int j = 0; j < 8; ++j) {
                    float sl = w00 * bf2f((ushort)c00[j]) + w01 * bf2f((ushort)c01[j])
                             + w10 * bf2f((ushort)c10[j]) + w11 * bf2f((ushort)c11[j]);
                    const float* xp = xb + ((long)(cin0 + j) << 14);
                    float sg = m00 * xp[i00] + m01 * xp[i01]
                             + m10 * xp[i10] + m11 * xp[i11];
                    d[j] = oob ? (sg - sl) : 0.f;
                }
                union { short8x v; ushort u[8]; } A;
#pragma unroll
                for (int j = 0; j < 8; ++j) A.u[j] = f2bf(d[j]);
#pragma unroll
                for (int nt = 0; nt < 4; ++nt) {
                    short8x bw = *(const short8x*)&Bd[(kk * 4 + nt) * 512 + (lane << 3)];
                    acc[nt] = __builtin_amdgcn_mfma_f32_16x16x32_bf16(A.v, bw, acc[nt], 0, 0, 0);
                }
            }
        }
    }

    // ---- epilogue (R5 verbatim): transpose D through LDS, coalesced stores
    __syncthreads();
    float* ob = (float*)tile;  // [64 px][65] f32 = 16640 B, aliases tile
#pragma unroll
    for (int nt = 0; nt < 4; ++nt) {
        int n = (nt << 4) + l15;
#pragma unroll
        for (int r = 0; r < 4; ++r) {
            int p = (wv << 4) + (lq << 2) + r;
            ob[p * 65 + n] = acc[nt][r];
        }
    }
    __syncthreads();
    {
        int n = tid >> 2, q = tid & 3;
        float bd = bdef[n];
        float* dst = out + (((long)(b * 64 + n)) << 14) + (h0 << 7) + w0;
#pragma unroll
        for (int rr = 0; rr < 2; ++rr) {
            int r = (q << 1) + rr;
            float v[8];
#pragma unroll
            for (int c = 0; c < 8; ++c) v[c] = ob[(r * 8 + c) * 65 + n] + bd;
            float4x s0 = {v[0], v[1], v[2], v[3]};
            float4x s1 = {v[4], v[5], v[6], v[7]};
            *(float4x*)(dst + (r << 7)) = s0;
            *(float4x*)(dst + (r << 7) + 4) = s1;
        }
    }
}

// ---------------------------------------------------------------------------
extern "C" void kernel_launch(void* const* d_in, const int* in_sizes, int n_in,
                              void* d_out, int out_size, void* d_ws, size_t ws_size,
                              hipStream_t stream) {
    const float* x     = (const float*)d_in[0];  // (4,64,128,128)
    const float* w_off = (const float*)d_in[1];  // (18,64,3,3)
    const float* b_off = (const float*)d_in[2];  // (18,)
    const float* w_def = (const float*)d_in[3];  // (64,64,3,3)
    const float* b_def = (const float*)d_in[4];  // (64,)
    float* out = (float*)d_out;                  // (4,64,128,128)

    ushort* Bd = (ushort*)d_ws;                  // 36864 bf16 = 73728 B
    ushort* Bo = Bd + 36864;                     // 18432 bf16 = 36864 B

    hipLaunchKernelGGL(pack_weights, dim3(216), dim3(256), 0, stream,
                       w_def, w_off, Bd, Bo);
    hipLaunchKernelGGL(dcn_fused, dim3(1024), dim3(256), 0, stream,
                       x, Bd, Bo, b_off, b_def, out);
}